// Round 14
// baseline (151.195 us; speedup 1.0000x reference)
//
#include <hip/hip_runtime.h>
#include <hip/hip_bf16.h>
#include <math.h>

#define B_  4
#define S_  2048
#define D_  512
#define H_  8
#define DK_ 64
#define BS_ (B_*S_)

using bf16x8 = __attribute__((ext_vector_type(8))) short;
using f32x4  = __attribute__((ext_vector_type(4))) float;
using f32x16 = __attribute__((ext_vector_type(16))) float;

typedef const __attribute__((address_space(1))) unsigned int gu32;
typedef __attribute__((address_space(3))) unsigned int lu32;

static __device__ inline float bf16f(unsigned short u) {
  union { unsigned u32; float f; } x; x.u32 = (unsigned)u << 16; return x.f;
}
// HW packed f32->bf16 (RNE), 1 VALU op for 2 values
static __device__ inline unsigned pk2(float a, float b) {
  unsigned r;
  asm("v_cvt_pk_bf16_f32 %0, %1, %2" : "=v"(r) : "v"(a), "v"(b));
  return r;
}
static __device__ inline float ex2(float a) {
  return __builtin_amdgcn_exp2f(a);   // raw v_exp_f32
}

// ---------------------------------------------------------------------------
// GEMM body with register-prefetch pipeline (unchanged from round 13).
// OUTMODE: 0 = f32 row-major, 1 = bf16 row-major, 2 = bf16 V^T [b][n][s].
// ---------------------------------------------------------------------------
template <int SPLIT, int OUTMODE>
static __device__ __forceinline__ void gemm_body(
    const float* __restrict__ A, const float* __restrict__ W,
    const float* __restrict__ bias, void* __restrict__ Cv,
    int bn, int bm, char* lds) {
  unsigned short (*As)[128][72] = (unsigned short(*)[128][72])lds;
  unsigned short (*Wt)[64][72] =
      (unsigned short(*)[64][72])(lds + (size_t)(SPLIT + 1) * 128 * 72 * 2);
  const int tid = threadIdx.x;
  const int wv = tid >> 6, lane = tid & 63;
  const int c = lane & 15, g = lane >> 4;

  f32x4 acc[2][4];
#pragma unroll
  for (int rt = 0; rt < 2; ++rt)
#pragma unroll
    for (int ds = 0; ds < 4; ++ds) acc[rt][ds] = f32x4{0.f, 0.f, 0.f, 0.f};

  const int arow = tid >> 1, ah = (tid & 1) * 32;
  const int wn = tid & 63, wkg = (tid >> 6) * 16;

  float af[32];   // prefetched A rows (f32)
  float wf[16];   // prefetched W column-slices (f32)

  auto LOADT = [&](int k0) {
    const float* ag = A + ((size_t)(bm * 128 + arow)) * D_ + k0 + ah;
#pragma unroll
    for (int i = 0; i < 8; ++i) *(float4*)&af[i * 4] = *(const float4*)(ag + i * 4);
    const float* wg = W + (size_t)(k0 + wkg) * D_ + bn * 64 + wn;
#pragma unroll
    for (int i = 0; i < 16; ++i) wf[i] = wg[(size_t)i * D_];
  };

  auto STORET = [&]() {
#pragma unroll
    for (int grp = 0; grp < 4; ++grp) {
      unsigned h[4], l[4];
#pragma unroll
      for (int p = 0; p < 4; ++p) {
        float f0 = af[grp * 8 + p * 2], f1 = af[grp * 8 + p * 2 + 1];
        h[p] = pk2(f0, f1);
        if constexpr (SPLIT)
          l[p] = pk2(f0 - bf16f((unsigned short)(h[p] & 0xffff)),
                     f1 - bf16f((unsigned short)(h[p] >> 16)));
      }
      uint4 uh; uh.x = h[0]; uh.y = h[1]; uh.z = h[2]; uh.w = h[3];
      *(uint4*)&As[0][arow][ah + grp * 8] = uh;
      if constexpr (SPLIT) {
        uint4 ul; ul.x = l[0]; ul.y = l[1]; ul.z = l[2]; ul.w = l[3];
        *(uint4*)&As[1][arow][ah + grp * 8] = ul;
      }
    }
#pragma unroll
    for (int grp = 0; grp < 2; ++grp) {
      unsigned h[4], l[4];
#pragma unroll
      for (int p = 0; p < 4; ++p) {
        float f0 = wf[grp * 8 + p * 2], f1 = wf[grp * 8 + p * 2 + 1];
        h[p] = pk2(f0, f1);
        if constexpr (SPLIT)
          l[p] = pk2(f0 - bf16f((unsigned short)(h[p] & 0xffff)),
                     f1 - bf16f((unsigned short)(h[p] >> 16)));
      }
      uint4 uh; uh.x = h[0]; uh.y = h[1]; uh.z = h[2]; uh.w = h[3];
      *(uint4*)&Wt[0][wn][wkg + grp * 8] = uh;
      if constexpr (SPLIT) {
        uint4 ul; ul.x = l[0]; ul.y = l[1]; ul.z = l[2]; ul.w = l[3];
        *(uint4*)&Wt[1][wn][wkg + grp * 8] = ul;
      }
    }
  };

  LOADT(0);
  for (int k0 = 0; k0 < D_; k0 += 64) {
    __syncthreads();        // prev MFMA done reading LDS
    STORET();               // waits the prefetched loads, packs, writes LDS
    __syncthreads();
    if (k0 + 64 < D_) LOADT(k0 + 64);   // flies under the MFMAs below

#pragma unroll
    for (int ksub = 0; ksub < 2; ++ksub) {
      bf16x8 bh[2], bl[2];
#pragma unroll
      for (int rt = 0; rt < 2; ++rt) {
        bh[rt] = *(const bf16x8*)&As[0][wv * 32 + rt * 16 + c][ksub * 32 + g * 8];
        if constexpr (SPLIT)
          bl[rt] = *(const bf16x8*)&As[1][wv * 32 + rt * 16 + c][ksub * 32 + g * 8];
      }
#pragma unroll
      for (int ds = 0; ds < 4; ++ds) {
        bf16x8 ah_ = *(const bf16x8*)&Wt[0][ds * 16 + c][ksub * 32 + g * 8];
#pragma unroll
        for (int rt = 0; rt < 2; ++rt)
          acc[rt][ds] = __builtin_amdgcn_mfma_f32_16x16x32_bf16(ah_, bh[rt], acc[rt][ds], 0, 0, 0);
        if constexpr (SPLIT) {
          bf16x8 al_ = *(const bf16x8*)&Wt[1][ds * 16 + c][ksub * 32 + g * 8];
#pragma unroll
          for (int rt = 0; rt < 2; ++rt) {
            acc[rt][ds] = __builtin_amdgcn_mfma_f32_16x16x32_bf16(ah_, bl[rt], acc[rt][ds], 0, 0, 0);
            acc[rt][ds] = __builtin_amdgcn_mfma_f32_16x16x32_bf16(al_, bh[rt], acc[rt][ds], 0, 0, 0);
          }
        }
      }
    }
  }

#pragma unroll
  for (int rt = 0; rt < 2; ++rt) {
    const size_t m = (size_t)bm * 128 + wv * 32 + rt * 16 + c;
#pragma unroll
    for (int ds = 0; ds < 4; ++ds) {
      const int n = bn * 64 + ds * 16 + 4 * g;
      float4 bv = *(const float4*)&bias[n];
      float o0 = acc[rt][ds][0] + bv.x, o1 = acc[rt][ds][1] + bv.y;
      float o2 = acc[rt][ds][2] + bv.z, o3 = acc[rt][ds][3] + bv.w;
      if constexpr (OUTMODE == 1) {
        uint2 p; p.x = pk2(o0, o1); p.y = pk2(o2, o3);
        *(uint2*)((unsigned short*)Cv + m * D_ + n) = p;
      } else if constexpr (OUTMODE == 2) {
        // V^T: [b][n][s]; b = m>>11, s = m&2047 (block never crosses batch)
        const unsigned u01 = pk2(o0, o1), u23 = pk2(o2, o3);
        unsigned short* base =
            (unsigned short*)Cv + ((size_t)(m >> 11) * D_ + n) * (size_t)S_ + (m & 2047);
        base[0]      = (unsigned short)u01;
        base[S_]     = (unsigned short)(u01 >> 16);
        base[2 * S_] = (unsigned short)u23;
        base[3 * S_] = (unsigned short)(u23 >> 16);
      } else {
        float4 o; o.x = o0; o.y = o1; o.z = o2; o.w = o3;
        *(float4*)((float*)Cv + m * D_ + n) = o;
      }
    }
  }
}

// ---------------------------------------------------------------------------
// Causal local-window (L=5) softmax pooling body; f32 or bf16 in, bf16 out.
// ---------------------------------------------------------------------------
template <int BF16IN>
static __device__ __forceinline__ void pool_body(
    const void* __restrict__ xv, unsigned short* __restrict__ out,
    float oscale, int bid) {
  const int gtid = bid * 256 + threadIdx.x;
  const int wave = gtid >> 6;
  const int lane = gtid & 63;
  const int b = wave / S_, s = wave % S_;
  const int d0 = lane * 8;
  float xi[8];
  float win[5][8];
  if constexpr (BF16IN) {
    const unsigned short* xrow =
        (const unsigned short*)xv + ((size_t)b * S_ + s) * D_ + d0;
    uint4 u = *(const uint4*)xrow;
#pragma unroll
    for (int t = 0; t < 4; ++t) {
      unsigned w_ = ((const unsigned*)&u)[t];
      xi[2 * t] = bf16f((unsigned short)(w_ & 0xffff));
      xi[2 * t + 1] = bf16f((unsigned short)(w_ >> 16));
    }
  } else {
    const float* xrow = (const float*)xv + ((size_t)b * S_ + s) * D_ + d0;
    *(float4*)&xi[0] = *(const float4*)xrow;
    *(float4*)&xi[4] = *(const float4*)(xrow + 4);
  }
  float sc[5];
#pragma unroll
  for (int j = 0; j < 5; ++j) {
    int src = s - 4 + j;
    float part = 0.f;
    if (src >= 0) {
      if constexpr (BF16IN) {
        const unsigned short* wr =
            (const unsigned short*)xv + ((size_t)b * S_ + src) * D_ + d0;
        uint4 u = *(const uint4*)wr;
#pragma unroll
        for (int t = 0; t < 4; ++t) {
          unsigned w_ = ((const unsigned*)&u)[t];
          win[j][2 * t] = bf16f((unsigned short)(w_ & 0xffff));
          win[j][2 * t + 1] = bf16f((unsigned short)(w_ >> 16));
        }
      } else {
        const float* wr = (const float*)xv + ((size_t)b * S_ + src) * D_ + d0;
        *(float4*)&win[j][0] = *(const float4*)wr;
        *(float4*)&win[j][4] = *(const float4*)(wr + 4);
      }
#pragma unroll
      for (int t = 0; t < 8; ++t) part += xi[t] * win[j][t];
    } else {
#pragma unroll
      for (int t = 0; t < 8; ++t) win[j][t] = 0.f;
    }
    sc[j] = part;
  }
#pragma unroll
  for (int off = 1; off < 64; off <<= 1) {
#pragma unroll
    for (int j = 0; j < 5; ++j) sc[j] += __shfl_xor(sc[j], off, 64);
  }
  const float scale = 0.04419417382415922f;  // 1/sqrt(512)
  float m = sc[0] * scale;
#pragma unroll
  for (int j = 1; j < 5; ++j) m = fmaxf(m, sc[j] * scale);
  float w[5], lsum = 0.f;
#pragma unroll
  for (int j = 0; j < 5; ++j) { w[j] = expf(sc[j] * scale - m); lsum += w[j]; }
  const float inv = oscale / lsum;
  float o[8] = {};
#pragma unroll
  for (int j = 0; j < 5; ++j)
#pragma unroll
    for (int t = 0; t < 8; ++t) o[t] += w[j] * win[j][t];
  unsigned short* orow = out + ((size_t)b * S_ + s) * D_;
  uint4 pk;
  pk.x = pk2(o[0] * inv, o[1] * inv);
  pk.y = pk2(o[2] * inv, o[3] * inv);
  pk.z = pk2(o[4] * inv, o[5] * inv);
  pk.w = pk2(o[6] * inv, o[7] * inv);
  *(uint4*)&orow[d0] = pk;
}

// ---------------------------------------------------------------------------
// Phase A (grid 3072): kfk plain GEMM -> bf16 (0..511), v GEMM -> V^T
// (512..1023), pool-q (1024..3071). Unchanged from round 13.
// ---------------------------------------------------------------------------
__global__ __launch_bounds__(256) void phaseA_kernel(
    const float* __restrict__ key, const float* __restrict__ W_fk,
    const float* __restrict__ b_fk, void* __restrict__ kfk_bf16,
    const float* __restrict__ value, const float* __restrict__ W0,
    const float* __restrict__ b0, void* __restrict__ vT,
    const float* __restrict__ query, unsigned short* __restrict__ qout,
    float qscale) {
  __shared__ __align__(16) char Lraw[27648];
  int bid = blockIdx.x;
  if (bid < 512) {
    gemm_body<0, 1>(key, W_fk, b_fk, kfk_bf16, bid & 7, bid >> 3, Lraw);
  } else if (bid < 1024) {
    bid -= 512;
    gemm_body<0, 2>(value, W0, b0, vT, bid & 7, bid >> 3, Lraw);
  } else {
    pool_body<0>(query, qout, qscale, bid - 1024);
  }
}

// Phase B: pool-k from bf16 kfk (2048 blocks).
__global__ __launch_bounds__(256) void pool_k_kernel(
    const unsigned short* __restrict__ kfk_bf16,
    unsigned short* __restrict__ kout) {
  pool_body<1>(kfk_bf16, kout, 1.0f, blockIdx.x);
}

// Final: out = x @ Wout + bout (split precision, register-prefetch).
__global__ __launch_bounds__(256) void gemm_out_kernel(
    const float* __restrict__ x, const float* __restrict__ Wout,
    const float* __restrict__ bout, float* __restrict__ out) {
  __shared__ __align__(16) char Lraw[55296];
  gemm_body<1, 0>(x, Wout, bout, out, blockIdx.x & 7, blockIdx.x >> 3, Lraw);
}

// ---------------------------------------------------------------------------
// 8-wave shared-stream MFMA flash attention (guide §B structure).
// Block = 512 threads = 8 waves, each owning 32 q-rows (QBLK=256/block).
// ALL waves share ONE double-buffered K/V stream: tiles of 64 keys, 32 tiles.
// LDS = Kb[2] + Vb[2] = 32KB. Grid = B*H*(S/256) = 256 blocks (1/CU).
// Per tile per wave: 1 K + 1 V global_load_lds (512thr x 16B = full 8KB tile
// each), QK^T -> softmax -> PV, ONE vmcnt(0)+barrier. No KV-split/combine.
// Staging swizzle (rule 21): linear LDS dest tid*16; global source chunk
// (tid&7)^((tid>>3)&7); reads XOR byte addr with ((row&7)<<4) as before.
// Hazards: RAW on buf ensured by prev tile's vmcnt(0)+barrier; WAR on buf^1
// ensured by the barrier (all reads of buf^1 finished at end of t-1).
// ---------------------------------------------------------------------------
__global__ __launch_bounds__(512) void attn8_kernel(
    const unsigned short* __restrict__ q, const unsigned short* __restrict__ k,
    const unsigned short* __restrict__ vt, float* __restrict__ x) {
  const int bid = (blockIdx.x & 7) * 32 + (blockIdx.x >> 3);  // XCD swizzle
  const int qb = bid & 7;              // 256-row q-block
  const int h  = (bid >> 3) & 7;
  const int b  = bid >> 6;
  const int tid = threadIdx.x;         // 0..511
  const int w = tid >> 6, l = tid & 63;
  const int ql = l & 31, hi = l >> 5;

  __shared__ __align__(16) unsigned short Kb[2][4096];  // 8KB x2
  __shared__ __align__(16) unsigned short Vb[2][4096];  // 8KB x2

  bf16x8 Qf[4];
  {
    const unsigned short* qg =
        q + ((size_t)b * S_ + qb * 256 + w * 32 + ql) * D_ + h * 64 + hi * 8;
#pragma unroll
    for (int f = 0; f < 4; ++f) Qf[f] = *(const bf16x8*)(qg + f * 16);
  }

  f32x16 accO[2] = {};           // O^T: [d-tile 32][q]
  float m = -INFINITY, lsum = 0.f;

  // staging: thread t covers row r_=t>>3 (0..63), phys chunk c_=t&7;
  // loads global chunk c_ ^ (r_&7) so swizzled reads see the right data.
  const int r_ = tid >> 3, c_ = tid & 7;
  const int swz = (c_ ^ (r_ & 7)) << 3;   // element offset within 64-elem row
  const unsigned short* kg =
      k + ((size_t)b * S_ + r_) * D_ + h * 64 + swz;
  const unsigned short* vg =
      vt + ((size_t)b * D_ + h * 64 + r_) * (size_t)S_ + swz;

  auto ISSUE = [&](int t, int bf) {
    __builtin_amdgcn_global_load_lds((gu32*)(kg + (size_t)t * 64 * D_),
                                     (lu32*)((char*)&Kb[bf][0] + tid * 16), 16, 0, 0);
    __builtin_amdgcn_global_load_lds((gu32*)(vg + t * 64),
                                     (lu32*)((char*)&Vb[bf][0] + tid * 16), 16, 0, 0);
  };

  // prologue: tile 0
  ISSUE(0, 0);
  asm volatile("s_waitcnt vmcnt(0)" ::: "memory");
  __builtin_amdgcn_s_barrier();
  __builtin_amdgcn_sched_barrier(0);

  int cur = 0;
  for (int kt = 0; kt < 32; ++kt) {
    if (kt + 1 < 32) ISSUE(kt + 1, cur ^ 1);   // flies under this tile's compute
    __builtin_amdgcn_sched_barrier(0);
    const char* KsB = (const char*)&Kb[cur][0];
    const char* VtB = (const char*)&Vb[cur][0];

    // ---- QK^T: two 32-key subtiles ----
    f32x16 sA = {}, sB = {};
    __builtin_amdgcn_s_setprio(1);
#pragma unroll
    for (int f = 0; f < 4; ++f) {
      bf16x8 a0 = *(const bf16x8*)(KsB + ((ql * 128 + f * 32 + hi * 16) ^ ((ql & 7) << 4)));
      bf16x8 a1 = *(const bf16x8*)(KsB + (((ql + 32) * 128 + f * 32 + hi * 16) ^ ((ql & 7) << 4)));
      sA = __builtin_amdgcn_mfma_f32_32x32x16_bf16(a0, Qf[f], sA, 0, 0, 0);
      sB = __builtin_amdgcn_mfma_f32_32x32x16_bf16(a1, Qf[f], sB, 0, 0, 0);
    }
    __builtin_amdgcn_s_setprio(0);

    // ---- tree max, defer-max THR=10 ----
    float mx[8];
#pragma unroll
    for (int r = 0; r < 8; ++r)
      mx[r] = fmaxf(fmaxf(sA[r], sA[r + 8]), fmaxf(sB[r], sB[r + 8]));
    mx[0] = fmaxf(mx[0], mx[4]); mx[1] = fmaxf(mx[1], mx[5]);
    mx[2] = fmaxf(mx[2], mx[6]); mx[3] = fmaxf(mx[3], mx[7]);
    mx[0] = fmaxf(fmaxf(mx[0], mx[1]), fmaxf(mx[2], mx[3]));
    const float mt = fmaxf(mx[0], __shfl_xor(mx[0], 32, 64));
    if (!__all(mt <= m + 10.0f)) {
      const float mn = fmaxf(m, mt);
      const float corr = ex2(m - mn);
      m = mn;
      lsum *= corr;
#pragma unroll
      for (int dt = 0; dt < 2; ++dt)
#pragma unroll
        for (int r = 0; r < 16; ++r) accO[dt][r] *= corr;
    }

    // ---- fused exp2 -> pack -> pairwise sum ----
    unsigned WA[8], WB[8];
    float s0 = 0.f, s1 = 0.f, s2 = 0.f, s3 = 0.f;
#pragma unroll
    for (int t = 0; t < 4; ++t) {
      float a0 = ex2(sA[4 * t + 0] - m), a1 = ex2(sA[4 * t + 1] - m);
      float a2 = ex2(sA[4 * t + 2] - m), a3 = ex2(sA[4 * t + 3] - m);
      WA[2 * t] = pk2(a0, a1); WA[2 * t + 1] = pk2(a2, a3);
      s0 += a0 + a1; s1 += a2 + a3;
      float b0 = ex2(sB[4 * t + 0] - m), b1 = ex2(sB[4 * t + 1] - m);
      float b2 = ex2(sB[4 * t + 2] - m), b3 = ex2(sB[4 * t + 3] - m);
      WB[2 * t] = pk2(b0, b1); WB[2 * t + 1] = pk2(b2, b3);
      s2 += b0 + b1; s3 += b2 + b3;
    }
    lsum += (s0 + s1) + (s2 + s3);

    // ---- PV: 4 key-chunks x 2 d-tiles ----
#pragma unroll
    for (int kc = 0; kc < 4; ++kc) {
      unsigned w0 = (kc < 2) ? WA[(kc & 1) * 4 + 0] : WB[(kc & 1) * 4 + 0];
      unsigned w1 = (kc < 2) ? WA[(kc & 1) * 4 + 1] : WB[(kc & 1) * 4 + 1];
      unsigned w2 = (kc < 2) ? WA[(kc & 1) * 4 + 2] : WB[(kc & 1) * 4 + 2];
      unsigned w3 = (kc < 2) ? WA[(kc & 1) * 4 + 3] : WB[(kc & 1) * 4 + 3];
      asm volatile("v_permlane32_swap_b32 %0, %1" : "+v"(w0), "+v"(w2));
      asm volatile("v_permlane32_swap_b32 %0, %1" : "+v"(w1), "+v"(w3));
      union { unsigned u[4]; bf16x8 v8; } pb;
      pb.u[0] = w0; pb.u[1] = w1; pb.u[2] = w2; pb.u[3] = w3;
      __builtin_amdgcn_s_setprio(1);
#pragma unroll
      for (int dt = 0; dt < 2; ++dt) {
        const int vrow = dt * 32 + ql;
        bf16x8 va = *(const bf16x8*)(VtB + ((vrow * 128 + kc * 32 + hi * 16) ^ ((ql & 7) << 4)));
        accO[dt] = __builtin_amdgcn_mfma_f32_32x32x16_bf16(va, pb.v8, accO[dt], 0, 0, 0);
      }
      __builtin_amdgcn_s_setprio(0);
    }

    // ---- single pipeline barrier: t+1 loads landed under compute ----
    asm volatile("s_waitcnt vmcnt(0)" ::: "memory");
    __builtin_amdgcn_s_barrier();
    __builtin_amdgcn_sched_barrier(0);
    cur ^= 1;
  }

  // ---- epilogue: per-wave, no combine ----
  const float ltot = lsum + __shfl_xor(lsum, 32, 64);
  const float inv = 1.f / ltot;
  float* xrow = x + ((size_t)b * S_ + qb * 256 + w * 32 + ql) * D_ + h * 64;
#pragma unroll
  for (int dt = 0; dt < 2; ++dt)
#pragma unroll
    for (int g0 = 0; g0 < 4; ++g0) {
      float4 o;
      o.x = accO[dt][4 * g0 + 0] * inv;
      o.y = accO[dt][4 * g0 + 1] * inv;
      o.z = accO[dt][4 * g0 + 2] * inv;
      o.w = accO[dt][4 * g0 + 3] * inv;
      *(float4*)&xrow[dt * 32 + hi * 4 + g0 * 8] = o;
    }
}

// ---------------------------------------------------------------------------
extern "C" void kernel_launch(void* const* d_in, const int* in_sizes, int n_in,
                              void* d_out, int out_size, void* d_ws, size_t ws_size,
                              hipStream_t stream) {
  const float* query = (const float*)d_in[0];
  const float* key   = (const float*)d_in[1];
  const float* value = (const float*)d_in[2];
  const float* W_fk = (const float*)d_in[4];
  const float* b_fk = (const float*)d_in[5];
  const float* W0   = (const float*)d_in[6];
  const float* b0   = (const float*)d_in[7];
  const float* Wout = (const float*)d_in[8];
  const float* bout = (const float*)d_in[9];
  float* out = (float*)d_out;

  char* ws = (char*)d_ws;
  unsigned short* kfk_bf16 = (unsigned short*)ws;                // 8MB @ 0
  float* x_f32   = (float*)(ws + (16u << 20));                   // 16MB @ 16MB
  unsigned short* k_bf16  = (unsigned short*)(ws + (32u << 20)); // 8MB @ 32MB
  unsigned short* vT_bf16 = (unsigned short*)(ws + (40u << 20)); // 8MB @ 40MB, [b][d][s]
  unsigned short* q_bf16  = (unsigned short*)(ws + (48u << 20)); // 8MB @ 48MB

  // 1/sqrt(dk) * log2(e): softmax runs in exp2 domain
  const float qscale = 0.125f * 1.4426950408889634f;

  // A: kfk GEMM || v GEMM -> V^T || pool-q (independent, overlapped)
  phaseA_kernel<<<3072, 256, 0, stream>>>(key, W_fk, b_fk, kfk_bf16,
                                          value, W0, b0, vT_bf16,
                                          query, q_bf16, qscale);
  // B: k = pool(kfk_bf16)
  pool_k_kernel<<<2048, 256, 0, stream>>>(kfk_bf16, k_bf16);
  // C: attention -> f32 (8-wave shared-stream)
  attn8_kernel<<<dim3(B_ * H_ * (S_ / 256)), 512, 0, stream>>>(
      q_bf16, k_bf16, vT_bf16, x_f32);
  // D: out = x @ Wout + bout (split)
  gemm_out_kernel<<<512, 256, 0, stream>>>(x_f32, Wout, bout, out);
}

// Round 15
// 148.081 us; speedup vs baseline: 1.0210x; 1.0210x over previous
//
#include <hip/hip_runtime.h>
#include <hip/hip_bf16.h>
#include <math.h>

#define B_  4
#define S_  2048
#define D_  512
#define H_  8
#define DK_ 64
#define BS_ (B_*S_)

using bf16x8 = __attribute__((ext_vector_type(8))) short;
using f32x4  = __attribute__((ext_vector_type(4))) float;
using f32x16 = __attribute__((ext_vector_type(16))) float;

typedef const __attribute__((address_space(1))) unsigned int gu32;
typedef __attribute__((address_space(3))) unsigned int lu32;

static __device__ inline float bf16f(unsigned short u) {
  union { unsigned u32; float f; } x; x.u32 = (unsigned)u << 16; return x.f;
}
// HW packed f32->bf16 (RNE), 1 VALU op for 2 values
static __device__ inline unsigned pk2(float a, float b) {
  unsigned r;
  asm("v_cvt_pk_bf16_f32 %0, %1, %2" : "=v"(r) : "v"(a), "v"(b));
  return r;
}
static __device__ inline float ex2(float a) {
  return __builtin_amdgcn_exp2f(a);   // raw v_exp_f32
}

// ---------------------------------------------------------------------------
// GEMM body with register-prefetch pipeline (unchanged from round 14).
// OUTMODE: 0 = f32 row-major, 1 = bf16 row-major, 2 = bf16 V^T [b][n][s].
// ---------------------------------------------------------------------------
template <int SPLIT, int OUTMODE>
static __device__ __forceinline__ void gemm_body(
    const float* __restrict__ A, const float* __restrict__ W,
    const float* __restrict__ bias, void* __restrict__ Cv,
    int bn, int bm, char* lds) {
  unsigned short (*As)[128][72] = (unsigned short(*)[128][72])lds;
  unsigned short (*Wt)[64][72] =
      (unsigned short(*)[64][72])(lds + (size_t)(SPLIT + 1) * 128 * 72 * 2);
  const int tid = threadIdx.x;
  const int wv = tid >> 6, lane = tid & 63;
  const int c = lane & 15, g = lane >> 4;

  f32x4 acc[2][4];
#pragma unroll
  for (int rt = 0; rt < 2; ++rt)
#pragma unroll
    for (int ds = 0; ds < 4; ++ds) acc[rt][ds] = f32x4{0.f, 0.f, 0.f, 0.f};

  const int arow = tid >> 1, ah = (tid & 1) * 32;
  const int wn = tid & 63, wkg = (tid >> 6) * 16;

  float af[32];   // prefetched A rows (f32)
  float wf[16];   // prefetched W column-slices (f32)

  auto LOADT = [&](int k0) {
    const float* ag = A + ((size_t)(bm * 128 + arow)) * D_ + k0 + ah;
#pragma unroll
    for (int i = 0; i < 8; ++i) *(float4*)&af[i * 4] = *(const float4*)(ag + i * 4);
    const float* wg = W + (size_t)(k0 + wkg) * D_ + bn * 64 + wn;
#pragma unroll
    for (int i = 0; i < 16; ++i) wf[i] = wg[(size_t)i * D_];
  };

  auto STORET = [&]() {
#pragma unroll
    for (int grp = 0; grp < 4; ++grp) {
      unsigned h[4], l[4];
#pragma unroll
      for (int p = 0; p < 4; ++p) {
        float f0 = af[grp * 8 + p * 2], f1 = af[grp * 8 + p * 2 + 1];
        h[p] = pk2(f0, f1);
        if constexpr (SPLIT)
          l[p] = pk2(f0 - bf16f((unsigned short)(h[p] & 0xffff)),
                     f1 - bf16f((unsigned short)(h[p] >> 16)));
      }
      uint4 uh; uh.x = h[0]; uh.y = h[1]; uh.z = h[2]; uh.w = h[3];
      *(uint4*)&As[0][arow][ah + grp * 8] = uh;
      if constexpr (SPLIT) {
        uint4 ul; ul.x = l[0]; ul.y = l[1]; ul.z = l[2]; ul.w = l[3];
        *(uint4*)&As[1][arow][ah + grp * 8] = ul;
      }
    }
#pragma unroll
    for (int grp = 0; grp < 2; ++grp) {
      unsigned h[4], l[4];
#pragma unroll
      for (int p = 0; p < 4; ++p) {
        float f0 = wf[grp * 8 + p * 2], f1 = wf[grp * 8 + p * 2 + 1];
        h[p] = pk2(f0, f1);
        if constexpr (SPLIT)
          l[p] = pk2(f0 - bf16f((unsigned short)(h[p] & 0xffff)),
                     f1 - bf16f((unsigned short)(h[p] >> 16)));
      }
      uint4 uh; uh.x = h[0]; uh.y = h[1]; uh.z = h[2]; uh.w = h[3];
      *(uint4*)&Wt[0][wn][wkg + grp * 8] = uh;
      if constexpr (SPLIT) {
        uint4 ul; ul.x = l[0]; ul.y = l[1]; ul.z = l[2]; ul.w = l[3];
        *(uint4*)&Wt[1][wn][wkg + grp * 8] = ul;
      }
    }
  };

  LOADT(0);
  for (int k0 = 0; k0 < D_; k0 += 64) {
    __syncthreads();        // prev MFMA done reading LDS
    STORET();               // waits the prefetched loads, packs, writes LDS
    __syncthreads();
    if (k0 + 64 < D_) LOADT(k0 + 64);   // flies under the MFMAs below

#pragma unroll
    for (int ksub = 0; ksub < 2; ++ksub) {
      bf16x8 bh[2], bl[2];
#pragma unroll
      for (int rt = 0; rt < 2; ++rt) {
        bh[rt] = *(const bf16x8*)&As[0][wv * 32 + rt * 16 + c][ksub * 32 + g * 8];
        if constexpr (SPLIT)
          bl[rt] = *(const bf16x8*)&As[1][wv * 32 + rt * 16 + c][ksub * 32 + g * 8];
      }
#pragma unroll
      for (int ds = 0; ds < 4; ++ds) {
        bf16x8 ah_ = *(const bf16x8*)&Wt[0][ds * 16 + c][ksub * 32 + g * 8];
#pragma unroll
        for (int rt = 0; rt < 2; ++rt)
          acc[rt][ds] = __builtin_amdgcn_mfma_f32_16x16x32_bf16(ah_, bh[rt], acc[rt][ds], 0, 0, 0);
        if constexpr (SPLIT) {
          bf16x8 al_ = *(const bf16x8*)&Wt[1][ds * 16 + c][ksub * 32 + g * 8];
#pragma unroll
          for (int rt = 0; rt < 2; ++rt) {
            acc[rt][ds] = __builtin_amdgcn_mfma_f32_16x16x32_bf16(ah_, bl[rt], acc[rt][ds], 0, 0, 0);
            acc[rt][ds] = __builtin_amdgcn_mfma_f32_16x16x32_bf16(al_, bh[rt], acc[rt][ds], 0, 0, 0);
          }
        }
      }
    }
  }

#pragma unroll
  for (int rt = 0; rt < 2; ++rt) {
    const size_t m = (size_t)bm * 128 + wv * 32 + rt * 16 + c;
#pragma unroll
    for (int ds = 0; ds < 4; ++ds) {
      const int n = bn * 64 + ds * 16 + 4 * g;
      float4 bv = *(const float4*)&bias[n];
      float o0 = acc[rt][ds][0] + bv.x, o1 = acc[rt][ds][1] + bv.y;
      float o2 = acc[rt][ds][2] + bv.z, o3 = acc[rt][ds][3] + bv.w;
      if constexpr (OUTMODE == 1) {
        uint2 p; p.x = pk2(o0, o1); p.y = pk2(o2, o3);
        *(uint2*)((unsigned short*)Cv + m * D_ + n) = p;
      } else if constexpr (OUTMODE == 2) {
        // V^T: [b][n][s]; b = m>>11, s = m&2047 (block never crosses batch)
        const unsigned u01 = pk2(o0, o1), u23 = pk2(o2, o3);
        unsigned short* base =
            (unsigned short*)Cv + ((size_t)(m >> 11) * D_ + n) * (size_t)S_ + (m & 2047);
        base[0]      = (unsigned short)u01;
        base[S_]     = (unsigned short)(u01 >> 16);
        base[2 * S_] = (unsigned short)u23;
        base[3 * S_] = (unsigned short)(u23 >> 16);
      } else {
        float4 o; o.x = o0; o.y = o1; o.z = o2; o.w = o3;
        *(float4*)((float*)Cv + m * D_ + n) = o;
      }
    }
  }
}

// ---------------------------------------------------------------------------
// Causal local-window (L=5) softmax pooling body; f32 or bf16 in, bf16 out.
// ---------------------------------------------------------------------------
template <int BF16IN>
static __device__ __forceinline__ void pool_body(
    const void* __restrict__ xv, unsigned short* __restrict__ out,
    float oscale, int bid) {
  const int gtid = bid * 256 + threadIdx.x;
  const int wave = gtid >> 6;
  const int lane = gtid & 63;
  const int b = wave / S_, s = wave % S_;
  const int d0 = lane * 8;
  float xi[8];
  float win[5][8];
  if constexpr (BF16IN) {
    const unsigned short* xrow =
        (const unsigned short*)xv + ((size_t)b * S_ + s) * D_ + d0;
    uint4 u = *(const uint4*)xrow;
#pragma unroll
    for (int t = 0; t < 4; ++t) {
      unsigned w_ = ((const unsigned*)&u)[t];
      xi[2 * t] = bf16f((unsigned short)(w_ & 0xffff));
      xi[2 * t + 1] = bf16f((unsigned short)(w_ >> 16));
    }
  } else {
    const float* xrow = (const float*)xv + ((size_t)b * S_ + s) * D_ + d0;
    *(float4*)&xi[0] = *(const float4*)xrow;
    *(float4*)&xi[4] = *(const float4*)(xrow + 4);
  }
  float sc[5];
#pragma unroll
  for (int j = 0; j < 5; ++j) {
    int src = s - 4 + j;
    float part = 0.f;
    if (src >= 0) {
      if constexpr (BF16IN) {
        const unsigned short* wr =
            (const unsigned short*)xv + ((size_t)b * S_ + src) * D_ + d0;
        uint4 u = *(const uint4*)wr;
#pragma unroll
        for (int t = 0; t < 4; ++t) {
          unsigned w_ = ((const unsigned*)&u)[t];
          win[j][2 * t] = bf16f((unsigned short)(w_ & 0xffff));
          win[j][2 * t + 1] = bf16f((unsigned short)(w_ >> 16));
        }
      } else {
        const float* wr = (const float*)xv + ((size_t)b * S_ + src) * D_ + d0;
        *(float4*)&win[j][0] = *(const float4*)wr;
        *(float4*)&win[j][4] = *(const float4*)(wr + 4);
      }
#pragma unroll
      for (int t = 0; t < 8; ++t) part += xi[t] * win[j][t];
    } else {
#pragma unroll
      for (int t = 0; t < 8; ++t) win[j][t] = 0.f;
    }
    sc[j] = part;
  }
#pragma unroll
  for (int off = 1; off < 64; off <<= 1) {
#pragma unroll
    for (int j = 0; j < 5; ++j) sc[j] += __shfl_xor(sc[j], off, 64);
  }
  const float scale = 0.04419417382415922f;  // 1/sqrt(512)
  float m = sc[0] * scale;
#pragma unroll
  for (int j = 1; j < 5; ++j) m = fmaxf(m, sc[j] * scale);
  float w[5], lsum = 0.f;
#pragma unroll
  for (int j = 0; j < 5; ++j) { w[j] = expf(sc[j] * scale - m); lsum += w[j]; }
  const float inv = oscale / lsum;
  float o[8] = {};
#pragma unroll
  for (int j = 0; j < 5; ++j)
#pragma unroll
    for (int t = 0; t < 8; ++t) o[t] += w[j] * win[j][t];
  unsigned short* orow = out + ((size_t)b * S_ + s) * D_;
  uint4 pk;
  pk.x = pk2(o[0] * inv, o[1] * inv);
  pk.y = pk2(o[2] * inv, o[3] * inv);
  pk.z = pk2(o[4] * inv, o[5] * inv);
  pk.w = pk2(o[6] * inv, o[7] * inv);
  *(uint4*)&orow[d0] = pk;
}

// ---------------------------------------------------------------------------
// Phase A (grid 3072): kfk plain GEMM -> bf16 (0..511), v GEMM -> V^T
// (512..1023), pool-q (1024..3071). Unchanged.
// ---------------------------------------------------------------------------
__global__ __launch_bounds__(256) void phaseA_kernel(
    const float* __restrict__ key, const float* __restrict__ W_fk,
    const float* __restrict__ b_fk, void* __restrict__ kfk_bf16,
    const float* __restrict__ value, const float* __restrict__ W0,
    const float* __restrict__ b0, void* __restrict__ vT,
    const float* __restrict__ query, unsigned short* __restrict__ qout,
    float qscale) {
  __shared__ __align__(16) char Lraw[27648];
  int bid = blockIdx.x;
  if (bid < 512) {
    gemm_body<0, 1>(key, W_fk, b_fk, kfk_bf16, bid & 7, bid >> 3, Lraw);
  } else if (bid < 1024) {
    bid -= 512;
    gemm_body<0, 2>(value, W0, b0, vT, bid & 7, bid >> 3, Lraw);
  } else {
    pool_body<0>(query, qout, qscale, bid - 1024);
  }
}

// Phase B: pool-k from bf16 kfk (2048 blocks).
__global__ __launch_bounds__(256) void pool_k_kernel(
    const unsigned short* __restrict__ kfk_bf16,
    unsigned short* __restrict__ kout) {
  pool_body<1>(kfk_bf16, kout, 1.0f, blockIdx.x);
}

// Final: out = x @ Wout + bout. PLAIN bf16 now (was split): x is an
// attention output (sigma ~ 0.05-0.1, softmax-averaged), so plain-bf16 GEMM
// error ~ sqrt(512)*sigma(x)*sigma(W)*2^-8 ~ 2-6e-4 << 3.75e-3 threshold.
// MFMA work /3 and LDS 55->27.6KB -> 4 blocks/CU.
__global__ __launch_bounds__(256) void gemm_out_kernel(
    const float* __restrict__ x, const float* __restrict__ Wout,
    const float* __restrict__ bout, float* __restrict__ out) {
  __shared__ __align__(16) char Lraw[27648];
  gemm_body<0, 0>(x, Wout, bout, out, blockIdx.x & 7, blockIdx.x >> 3, Lraw);
}

// ---------------------------------------------------------------------------
// 8-wave shared-stream MFMA flash attention (unchanged from round 14).
// ---------------------------------------------------------------------------
__global__ __launch_bounds__(512) void attn8_kernel(
    const unsigned short* __restrict__ q, const unsigned short* __restrict__ k,
    const unsigned short* __restrict__ vt, float* __restrict__ x) {
  const int bid = (blockIdx.x & 7) * 32 + (blockIdx.x >> 3);  // XCD swizzle
  const int qb = bid & 7;              // 256-row q-block
  const int h  = (bid >> 3) & 7;
  const int b  = bid >> 6;
  const int tid = threadIdx.x;         // 0..511
  const int w = tid >> 6, l = tid & 63;
  const int ql = l & 31, hi = l >> 5;

  __shared__ __align__(16) unsigned short Kb[2][4096];  // 8KB x2
  __shared__ __align__(16) unsigned short Vb[2][4096];  // 8KB x2

  bf16x8 Qf[4];
  {
    const unsigned short* qg =
        q + ((size_t)b * S_ + qb * 256 + w * 32 + ql) * D_ + h * 64 + hi * 8;
#pragma unroll
    for (int f = 0; f < 4; ++f) Qf[f] = *(const bf16x8*)(qg + f * 16);
  }

  f32x16 accO[2] = {};           // O^T: [d-tile 32][q]
  float m = -INFINITY, lsum = 0.f;

  const int r_ = tid >> 3, c_ = tid & 7;
  const int swz = (c_ ^ (r_ & 7)) << 3;
  const unsigned short* kg =
      k + ((size_t)b * S_ + r_) * D_ + h * 64 + swz;
  const unsigned short* vg =
      vt + ((size_t)b * D_ + h * 64 + r_) * (size_t)S_ + swz;

  auto ISSUE = [&](int t, int bf) {
    __builtin_amdgcn_global_load_lds((gu32*)(kg + (size_t)t * 64 * D_),
                                     (lu32*)((char*)&Kb[bf][0] + tid * 16), 16, 0, 0);
    __builtin_amdgcn_global_load_lds((gu32*)(vg + t * 64),
                                     (lu32*)((char*)&Vb[bf][0] + tid * 16), 16, 0, 0);
  };

  ISSUE(0, 0);
  asm volatile("s_waitcnt vmcnt(0)" ::: "memory");
  __builtin_amdgcn_s_barrier();
  __builtin_amdgcn_sched_barrier(0);

  int cur = 0;
  for (int kt = 0; kt < 32; ++kt) {
    if (kt + 1 < 32) ISSUE(kt + 1, cur ^ 1);
    __builtin_amdgcn_sched_barrier(0);
    const char* KsB = (const char*)&Kb[cur][0];
    const char* VtB = (const char*)&Vb[cur][0];

    f32x16 sA = {}, sB = {};
    __builtin_amdgcn_s_setprio(1);
#pragma unroll
    for (int f = 0; f < 4; ++f) {
      bf16x8 a0 = *(const bf16x8*)(KsB + ((ql * 128 + f * 32 + hi * 16) ^ ((ql & 7) << 4)));
      bf16x8 a1 = *(const bf16x8*)(KsB + (((ql + 32) * 128 + f * 32 + hi * 16) ^ ((ql & 7) << 4)));
      sA = __builtin_amdgcn_mfma_f32_32x32x16_bf16(a0, Qf[f], sA, 0, 0, 0);
      sB = __builtin_amdgcn_mfma_f32_32x32x16_bf16(a1, Qf[f], sB, 0, 0, 0);
    }
    __builtin_amdgcn_s_setprio(0);

    float mx[8];
#pragma unroll
    for (int r = 0; r < 8; ++r)
      mx[r] = fmaxf(fmaxf(sA[r], sA[r + 8]), fmaxf(sB[r], sB[r + 8]));
    mx[0] = fmaxf(mx[0], mx[4]); mx[1] = fmaxf(mx[1], mx[5]);
    mx[2] = fmaxf(mx[2], mx[6]); mx[3] = fmaxf(mx[3], mx[7]);
    mx[0] = fmaxf(fmaxf(mx[0], mx[1]), fmaxf(mx[2], mx[3]));
    const float mt = fmaxf(mx[0], __shfl_xor(mx[0], 32, 64));
    if (!__all(mt <= m + 10.0f)) {
      const float mn = fmaxf(m, mt);
      const float corr = ex2(m - mn);
      m = mn;
      lsum *= corr;
#pragma unroll
      for (int dt = 0; dt < 2; ++dt)
#pragma unroll
        for (int r = 0; r < 16; ++r) accO[dt][r] *= corr;
    }

    unsigned WA[8], WB[8];
    float s0 = 0.f, s1 = 0.f, s2 = 0.f, s3 = 0.f;
#pragma unroll
    for (int t = 0; t < 4; ++t) {
      float a0 = ex2(sA[4 * t + 0] - m), a1 = ex2(sA[4 * t + 1] - m);
      float a2 = ex2(sA[4 * t + 2] - m), a3 = ex2(sA[4 * t + 3] - m);
      WA[2 * t] = pk2(a0, a1); WA[2 * t + 1] = pk2(a2, a3);
      s0 += a0 + a1; s1 += a2 + a3;
      float b0 = ex2(sB[4 * t + 0] - m), b1 = ex2(sB[4 * t + 1] - m);
      float b2 = ex2(sB[4 * t + 2] - m), b3 = ex2(sB[4 * t + 3] - m);
      WB[2 * t] = pk2(b0, b1); WB[2 * t + 1] = pk2(b2, b3);
      s2 += b0 + b1; s3 += b2 + b3;
    }
    lsum += (s0 + s1) + (s2 + s3);

#pragma unroll
    for (int kc = 0; kc < 4; ++kc) {
      unsigned w0 = (kc < 2) ? WA[(kc & 1) * 4 + 0] : WB[(kc & 1) * 4 + 0];
      unsigned w1 = (kc < 2) ? WA[(kc & 1) * 4 + 1] : WB[(kc & 1) * 4 + 1];
      unsigned w2 = (kc < 2) ? WA[(kc & 1) * 4 + 2] : WB[(kc & 1) * 4 + 2];
      unsigned w3 = (kc < 2) ? WA[(kc & 1) * 4 + 3] : WB[(kc & 1) * 4 + 3];
      asm volatile("v_permlane32_swap_b32 %0, %1" : "+v"(w0), "+v"(w2));
      asm volatile("v_permlane32_swap_b32 %0, %1" : "+v"(w1), "+v"(w3));
      union { unsigned u[4]; bf16x8 v8; } pb;
      pb.u[0] = w0; pb.u[1] = w1; pb.u[2] = w2; pb.u[3] = w3;
      __builtin_amdgcn_s_setprio(1);
#pragma unroll
      for (int dt = 0; dt < 2; ++dt) {
        const int vrow = dt * 32 + ql;
        bf16x8 va = *(const bf16x8*)(VtB + ((vrow * 128 + kc * 32 + hi * 16) ^ ((ql & 7) << 4)));
        accO[dt] = __builtin_amdgcn_mfma_f32_32x32x16_bf16(va, pb.v8, accO[dt], 0, 0, 0);
      }
      __builtin_amdgcn_s_setprio(0);
    }

    asm volatile("s_waitcnt vmcnt(0)" ::: "memory");
    __builtin_amdgcn_s_barrier();
    __builtin_amdgcn_sched_barrier(0);
    cur ^= 1;
  }

  const float ltot = lsum + __shfl_xor(lsum, 32, 64);
  const float inv = 1.f / ltot;
  float* xrow = x + ((size_t)b * S_ + qb * 256 + w * 32 + ql) * D_ + h * 64;
#pragma unroll
  for (int dt = 0; dt < 2; ++dt)
#pragma unroll
    for (int g0 = 0; g0 < 4; ++g0) {
      float4 o;
      o.x = accO[dt][4 * g0 + 0] * inv;
      o.y = accO[dt][4 * g0 + 1] * inv;
      o.z = accO[dt][4 * g0 + 2] * inv;
      o.w = accO[dt][4 * g0 + 3] * inv;
      *(float4*)&xrow[dt * 32 + hi * 4 + g0 * 8] = o;
    }
}

// ---------------------------------------------------------------------------
extern "C" void kernel_launch(void* const* d_in, const int* in_sizes, int n_in,
                              void* d_out, int out_size, void* d_ws, size_t ws_size,
                              hipStream_t stream) {
  const float* query = (const float*)d_in[0];
  const float* key   = (const float*)d_in[1];
  const float* value = (const float*)d_in[2];
  const float* W_fk = (const float*)d_in[4];
  const float* b_fk = (const float*)d_in[5];
  const float* W0   = (const float*)d_in[6];
  const float* b0   = (const float*)d_in[7];
  const float* Wout = (const float*)d_in[8];
  const float* bout = (const float*)d_in[9];
  float* out = (float*)d_out;

  char* ws = (char*)d_ws;
  unsigned short* kfk_bf16 = (unsigned short*)ws;                // 8MB @ 0
  float* x_f32   = (float*)(ws + (16u << 20));                   // 16MB @ 16MB
  unsigned short* k_bf16  = (unsigned short*)(ws + (32u << 20)); // 8MB @ 32MB
  unsigned short* vT_bf16 = (unsigned short*)(ws + (40u << 20)); // 8MB @ 40MB, [b][d][s]
  unsigned short* q_bf16  = (unsigned short*)(ws + (48u << 20)); // 8MB @ 48MB

  // 1/sqrt(dk) * log2(e): softmax runs in exp2 domain
  const float qscale = 0.125f * 1.4426950408889634f;

  // A: kfk GEMM || v GEMM -> V^T || pool-q (independent, overlapped)
  phaseA_kernel<<<3072, 256, 0, stream>>>(key, W_fk, b_fk, kfk_bf16,
                                          value, W0, b0, vT_bf16,
                                          query, q_bf16, qscale);
  // B: k = pool(kfk_bf16)
  pool_k_kernel<<<2048, 256, 0, stream>>>(kfk_bf16, k_bf16);
  // C: attention -> f32 (8-wave shared-stream)
  attn8_kernel<<<dim3(B_ * H_ * (S_ / 256)), 512, 0, stream>>>(
      q_bf16, k_bf16, vT_bf16, x_f32);
  // D: out = x @ Wout + bout (plain bf16)
  gemm_out_kernel<<<512, 256, 0, stream>>>(x_f32, Wout, bout, out);
}

// Round 16
// 148.073 us; speedup vs baseline: 1.0211x; 1.0001x over previous
//
#include <hip/hip_runtime.h>
#include <hip/hip_bf16.h>
#include <math.h>

#define B_  4
#define S_  2048
#define D_  512
#define H_  8
#define DK_ 64
#define BS_ (B_*S_)

using bf16x8 = __attribute__((ext_vector_type(8))) short;
using f32x4  = __attribute__((ext_vector_type(4))) float;
using f32x16 = __attribute__((ext_vector_type(16))) float;

typedef const __attribute__((address_space(1))) unsigned int gu32;
typedef __attribute__((address_space(3))) unsigned int lu32;

static __device__ inline float bf16f(unsigned short u) {
  union { unsigned u32; float f; } x; x.u32 = (unsigned)u << 16; return x.f;
}
// HW packed f32->bf16 (RNE), 1 VALU op for 2 values
static __device__ inline unsigned pk2(float a, float b) {
  unsigned r;
  asm("v_cvt_pk_bf16_f32 %0, %1, %2" : "=v"(r) : "v"(a), "v"(b));
  return r;
}
static __device__ inline float ex2(float a) {
  return __builtin_amdgcn_exp2f(a);   // raw v_exp_f32
}

// ---------------------------------------------------------------------------
// GEMM body with register-prefetch pipeline (unchanged).
// OUTMODE: 0 = f32 row-major, 1 = bf16 row-major, 2 = bf16 V^T [b][n][s].
// ---------------------------------------------------------------------------
template <int SPLIT, int OUTMODE>
static __device__ __forceinline__ void gemm_body(
    const float* __restrict__ A, const float* __restrict__ W,
    const float* __restrict__ bias, void* __restrict__ Cv,
    int bn, int bm, char* lds) {
  unsigned short (*As)[128][72] = (unsigned short(*)[128][72])lds;
  unsigned short (*Wt)[64][72] =
      (unsigned short(*)[64][72])(lds + (size_t)(SPLIT + 1) * 128 * 72 * 2);
  const int tid = threadIdx.x;
  const int wv = tid >> 6, lane = tid & 63;
  const int c = lane & 15, g = lane >> 4;

  f32x4 acc[2][4];
#pragma unroll
  for (int rt = 0; rt < 2; ++rt)
#pragma unroll
    for (int ds = 0; ds < 4; ++ds) acc[rt][ds] = f32x4{0.f, 0.f, 0.f, 0.f};

  const int arow = tid >> 1, ah = (tid & 1) * 32;
  const int wn = tid & 63, wkg = (tid >> 6) * 16;

  float af[32];   // prefetched A rows (f32)
  float wf[16];   // prefetched W column-slices (f32)

  auto LOADT = [&](int k0) {
    const float* ag = A + ((size_t)(bm * 128 + arow)) * D_ + k0 + ah;
#pragma unroll
    for (int i = 0; i < 8; ++i) *(float4*)&af[i * 4] = *(const float4*)(ag + i * 4);
    const float* wg = W + (size_t)(k0 + wkg) * D_ + bn * 64 + wn;
#pragma unroll
    for (int i = 0; i < 16; ++i) wf[i] = wg[(size_t)i * D_];
  };

  auto STORET = [&]() {
#pragma unroll
    for (int grp = 0; grp < 4; ++grp) {
      unsigned h[4], l[4];
#pragma unroll
      for (int p = 0; p < 4; ++p) {
        float f0 = af[grp * 8 + p * 2], f1 = af[grp * 8 + p * 2 + 1];
        h[p] = pk2(f0, f1);
        if constexpr (SPLIT)
          l[p] = pk2(f0 - bf16f((unsigned short)(h[p] & 0xffff)),
                     f1 - bf16f((unsigned short)(h[p] >> 16)));
      }
      uint4 uh; uh.x = h[0]; uh.y = h[1]; uh.z = h[2]; uh.w = h[3];
      *(uint4*)&As[0][arow][ah + grp * 8] = uh;
      if constexpr (SPLIT) {
        uint4 ul; ul.x = l[0]; ul.y = l[1]; ul.z = l[2]; ul.w = l[3];
        *(uint4*)&As[1][arow][ah + grp * 8] = ul;
      }
    }
#pragma unroll
    for (int grp = 0; grp < 2; ++grp) {
      unsigned h[4], l[4];
#pragma unroll
      for (int p = 0; p < 4; ++p) {
        float f0 = wf[grp * 8 + p * 2], f1 = wf[grp * 8 + p * 2 + 1];
        h[p] = pk2(f0, f1);
        if constexpr (SPLIT)
          l[p] = pk2(f0 - bf16f((unsigned short)(h[p] & 0xffff)),
                     f1 - bf16f((unsigned short)(h[p] >> 16)));
      }
      uint4 uh; uh.x = h[0]; uh.y = h[1]; uh.z = h[2]; uh.w = h[3];
      *(uint4*)&Wt[0][wn][wkg + grp * 8] = uh;
      if constexpr (SPLIT) {
        uint4 ul; ul.x = l[0]; ul.y = l[1]; ul.z = l[2]; ul.w = l[3];
        *(uint4*)&Wt[1][wn][wkg + grp * 8] = ul;
      }
    }
  };

  LOADT(0);
  for (int k0 = 0; k0 < D_; k0 += 64) {
    __syncthreads();        // prev MFMA done reading LDS
    STORET();               // waits the prefetched loads, packs, writes LDS
    __syncthreads();
    if (k0 + 64 < D_) LOADT(k0 + 64);   // flies under the MFMAs below

#pragma unroll
    for (int ksub = 0; ksub < 2; ++ksub) {
      bf16x8 bh[2], bl[2];
#pragma unroll
      for (int rt = 0; rt < 2; ++rt) {
        bh[rt] = *(const bf16x8*)&As[0][wv * 32 + rt * 16 + c][ksub * 32 + g * 8];
        if constexpr (SPLIT)
          bl[rt] = *(const bf16x8*)&As[1][wv * 32 + rt * 16 + c][ksub * 32 + g * 8];
      }
#pragma unroll
      for (int ds = 0; ds < 4; ++ds) {
        bf16x8 ah_ = *(const bf16x8*)&Wt[0][ds * 16 + c][ksub * 32 + g * 8];
#pragma unroll
        for (int rt = 0; rt < 2; ++rt)
          acc[rt][ds] = __builtin_amdgcn_mfma_f32_16x16x32_bf16(ah_, bh[rt], acc[rt][ds], 0, 0, 0);
        if constexpr (SPLIT) {
          bf16x8 al_ = *(const bf16x8*)&Wt[1][ds * 16 + c][ksub * 32 + g * 8];
#pragma unroll
          for (int rt = 0; rt < 2; ++rt) {
            acc[rt][ds] = __builtin_amdgcn_mfma_f32_16x16x32_bf16(ah_, bl[rt], acc[rt][ds], 0, 0, 0);
            acc[rt][ds] = __builtin_amdgcn_mfma_f32_16x16x32_bf16(al_, bh[rt], acc[rt][ds], 0, 0, 0);
          }
        }
      }
    }
  }

#pragma unroll
  for (int rt = 0; rt < 2; ++rt) {
    const size_t m = (size_t)bm * 128 + wv * 32 + rt * 16 + c;
#pragma unroll
    for (int ds = 0; ds < 4; ++ds) {
      const int n = bn * 64 + ds * 16 + 4 * g;
      float4 bv = *(const float4*)&bias[n];
      float o0 = acc[rt][ds][0] + bv.x, o1 = acc[rt][ds][1] + bv.y;
      float o2 = acc[rt][ds][2] + bv.z, o3 = acc[rt][ds][3] + bv.w;
      if constexpr (OUTMODE == 1) {
        uint2 p; p.x = pk2(o0, o1); p.y = pk2(o2, o3);
        *(uint2*)((unsigned short*)Cv + m * D_ + n) = p;
      } else if constexpr (OUTMODE == 2) {
        // V^T: [b][n][s]; b = m>>11, s = m&2047 (block never crosses batch)
        const unsigned u01 = pk2(o0, o1), u23 = pk2(o2, o3);
        unsigned short* base =
            (unsigned short*)Cv + ((size_t)(m >> 11) * D_ + n) * (size_t)S_ + (m & 2047);
        base[0]      = (unsigned short)u01;
        base[S_]     = (unsigned short)(u01 >> 16);
        base[2 * S_] = (unsigned short)u23;
        base[3 * S_] = (unsigned short)(u23 >> 16);
      } else {
        float4 o; o.x = o0; o.y = o1; o.z = o2; o.w = o3;
        *(float4*)((float*)Cv + m * D_ + n) = o;
      }
    }
  }
}

// ---------------------------------------------------------------------------
// Causal local-window (L=5) softmax pooling body; f32 or bf16 in, bf16 out.
// ---------------------------------------------------------------------------
template <int BF16IN>
static __device__ __forceinline__ void pool_body(
    const void* __restrict__ xv, unsigned short* __restrict__ out,
    float oscale, int bid) {
  const int gtid = bid * 256 + threadIdx.x;
  const int wave = gtid >> 6;
  const int lane = gtid & 63;
  const int b = wave / S_, s = wave % S_;
  const int d0 = lane * 8;
  float xi[8];
  float win[5][8];
  if constexpr (BF16IN) {
    const unsigned short* xrow =
        (const unsigned short*)xv + ((size_t)b * S_ + s) * D_ + d0;
    uint4 u = *(const uint4*)xrow;
#pragma unroll
    for (int t = 0; t < 4; ++t) {
      unsigned w_ = ((const unsigned*)&u)[t];
      xi[2 * t] = bf16f((unsigned short)(w_ & 0xffff));
      xi[2 * t + 1] = bf16f((unsigned short)(w_ >> 16));
    }
  } else {
    const float* xrow = (const float*)xv + ((size_t)b * S_ + s) * D_ + d0;
    *(float4*)&xi[0] = *(const float4*)xrow;
    *(float4*)&xi[4] = *(const float4*)(xrow + 4);
  }
  float sc[5];
#pragma unroll
  for (int j = 0; j < 5; ++j) {
    int src = s - 4 + j;
    float part = 0.f;
    if (src >= 0) {
      if constexpr (BF16IN) {
        const unsigned short* wr =
            (const unsigned short*)xv + ((size_t)b * S_ + src) * D_ + d0;
        uint4 u = *(const uint4*)wr;
#pragma unroll
        for (int t = 0; t < 4; ++t) {
          unsigned w_ = ((const unsigned*)&u)[t];
          win[j][2 * t] = bf16f((unsigned short)(w_ & 0xffff));
          win[j][2 * t + 1] = bf16f((unsigned short)(w_ >> 16));
        }
      } else {
        const float* wr = (const float*)xv + ((size_t)b * S_ + src) * D_ + d0;
        *(float4*)&win[j][0] = *(const float4*)wr;
        *(float4*)&win[j][4] = *(const float4*)(wr + 4);
      }
#pragma unroll
      for (int t = 0; t < 8; ++t) part += xi[t] * win[j][t];
    } else {
#pragma unroll
      for (int t = 0; t < 8; ++t) win[j][t] = 0.f;
    }
    sc[j] = part;
  }
#pragma unroll
  for (int off = 1; off < 64; off <<= 1) {
#pragma unroll
    for (int j = 0; j < 5; ++j) sc[j] += __shfl_xor(sc[j], off, 64);
  }
  const float scale = 0.04419417382415922f;  // 1/sqrt(512)
  float m = sc[0] * scale;
#pragma unroll
  for (int j = 1; j < 5; ++j) m = fmaxf(m, sc[j] * scale);
  float w[5], lsum = 0.f;
#pragma unroll
  for (int j = 0; j < 5; ++j) { w[j] = expf(sc[j] * scale - m); lsum += w[j]; }
  const float inv = oscale / lsum;
  float o[8] = {};
#pragma unroll
  for (int j = 0; j < 5; ++j)
#pragma unroll
    for (int t = 0; t < 8; ++t) o[t] += w[j] * win[j][t];
  unsigned short* orow = out + ((size_t)b * S_ + s) * D_;
  uint4 pk;
  pk.x = pk2(o[0] * inv, o[1] * inv);
  pk.y = pk2(o[2] * inv, o[3] * inv);
  pk.z = pk2(o[4] * inv, o[5] * inv);
  pk.w = pk2(o[6] * inv, o[7] * inv);
  *(uint4*)&orow[d0] = pk;
}

// ---------------------------------------------------------------------------
// Phase A (grid 3072): kfk plain GEMM -> bf16 (0..511), v GEMM -> V^T
// (512..1023), pool-q (1024..3071). Unchanged.
// ---------------------------------------------------------------------------
__global__ __launch_bounds__(256) void phaseA_kernel(
    const float* __restrict__ key, const float* __restrict__ W_fk,
    const float* __restrict__ b_fk, void* __restrict__ kfk_bf16,
    const float* __restrict__ value, const float* __restrict__ W0,
    const float* __restrict__ b0, void* __restrict__ vT,
    const float* __restrict__ query, unsigned short* __restrict__ qout,
    float qscale) {
  __shared__ __align__(16) char Lraw[27648];
  int bid = blockIdx.x;
  if (bid < 512) {
    gemm_body<0, 1>(key, W_fk, b_fk, kfk_bf16, bid & 7, bid >> 3, Lraw);
  } else if (bid < 1024) {
    bid -= 512;
    gemm_body<0, 2>(value, W0, b0, vT, bid & 7, bid >> 3, Lraw);
  } else {
    pool_body<0>(query, qout, qscale, bid - 1024);
  }
}

// Phase B: pool-k from bf16 kfk (2048 blocks).
__global__ __launch_bounds__(256) void pool_k_kernel(
    const unsigned short* __restrict__ kfk_bf16,
    unsigned short* __restrict__ kout) {
  pool_body<1>(kfk_bf16, kout, 1.0f, blockIdx.x);
}

// Final: out = x @ Wout + bout (plain bf16; unchanged from round 15).
__global__ __launch_bounds__(256) void gemm_out_kernel(
    const float* __restrict__ x, const float* __restrict__ Wout,
    const float* __restrict__ bout, float* __restrict__ out) {
  __shared__ __align__(16) char Lraw[27648];
  gemm_body<0, 0>(x, Wout, bout, out, blockIdx.x & 7, blockIdx.x >> 3, Lraw);
}

// ---------------------------------------------------------------------------
// 8-wave shared-stream MFMA flash attention.
// Round-15 structure + TWO regalloc fixes:
//  (1) __launch_bounds__(512, 2): grid=256 blocks is 1 block/CU = 2 waves/
//      SIMD regardless, but without the hint the compiler capped at 60 VGPR
//      (8-wave target) and rematerialized ~24 swizzled LDS addresses every
//      tile -> ~3x VALU bloat. The (512,2) cap (256 VGPR) matches reality.
//  (2) LDS read offsets hoisted into registers (compile-time-indexed in
//      unrolled loops -> stays in VGPRs, no scratch).
// Math bit-identical to round 15.
// ---------------------------------------------------------------------------
__global__ __launch_bounds__(512, 2) void attn8_kernel(
    const unsigned short* __restrict__ q, const unsigned short* __restrict__ k,
    const unsigned short* __restrict__ vt, float* __restrict__ x) {
  const int bid = (blockIdx.x & 7) * 32 + (blockIdx.x >> 3);  // XCD swizzle
  const int qb = bid & 7;              // 256-row q-block
  const int h  = (bid >> 3) & 7;
  const int b  = bid >> 6;
  const int tid = threadIdx.x;         // 0..511
  const int w = tid >> 6, l = tid & 63;
  const int ql = l & 31, hi = l >> 5;

  __shared__ __align__(16) unsigned short Kb[2][4096];  // 8KB x2
  __shared__ __align__(16) unsigned short Vb[2][4096];  // 8KB x2

  bf16x8 Qf[4];
  {
    const unsigned short* qg =
        q + ((size_t)b * S_ + qb * 256 + w * 32 + ql) * D_ + h * 64 + hi * 8;
#pragma unroll
    for (int f = 0; f < 4; ++f) Qf[f] = *(const bf16x8*)(qg + f * 16);
  }

  f32x16 accO[2] = {};           // O^T: [d-tile 32][q]
  float m = -INFINITY, lsum = 0.f;

  // hoisted LDS read offsets (compile-time-indexed -> registers)
  const int xorm = (ql & 7) << 4;
  int kOffA[4], kOffB[4], vOff[4][2];
#pragma unroll
  for (int f = 0; f < 4; ++f) {
    kOffA[f] = (ql * 128 + f * 32 + hi * 16) ^ xorm;
    kOffB[f] = ((ql + 32) * 128 + f * 32 + hi * 16) ^ xorm;  // (ql+32)&7==ql&7
  }
#pragma unroll
  for (int kc = 0; kc < 4; ++kc)
#pragma unroll
    for (int dt = 0; dt < 2; ++dt)
      vOff[kc][dt] = ((dt * 32 + ql) * 128 + kc * 32 + hi * 16) ^ xorm;

  const int r_ = tid >> 3, c_ = tid & 7;
  const int swz = (c_ ^ (r_ & 7)) << 3;
  const unsigned short* kg =
      k + ((size_t)b * S_ + r_) * D_ + h * 64 + swz;
  const unsigned short* vg =
      vt + ((size_t)b * D_ + h * 64 + r_) * (size_t)S_ + swz;

  auto ISSUE = [&](int t, int bf) {
    __builtin_amdgcn_global_load_lds((gu32*)(kg + (size_t)t * 64 * D_),
                                     (lu32*)((char*)&Kb[bf][0] + tid * 16), 16, 0, 0);
    __builtin_amdgcn_global_load_lds((gu32*)(vg + t * 64),
                                     (lu32*)((char*)&Vb[bf][0] + tid * 16), 16, 0, 0);
  };

  ISSUE(0, 0);
  asm volatile("s_waitcnt vmcnt(0)" ::: "memory");
  __builtin_amdgcn_s_barrier();
  __builtin_amdgcn_sched_barrier(0);

  int cur = 0;
  for (int kt = 0; kt < 32; ++kt) {
    if (kt + 1 < 32) ISSUE(kt + 1, cur ^ 1);
    __builtin_amdgcn_sched_barrier(0);
    const char* KsB = (const char*)&Kb[cur][0];
    const char* VtB = (const char*)&Vb[cur][0];

    f32x16 sA = {}, sB = {};
    __builtin_amdgcn_s_setprio(1);
#pragma unroll
    for (int f = 0; f < 4; ++f) {
      bf16x8 a0 = *(const bf16x8*)(KsB + kOffA[f]);
      bf16x8 a1 = *(const bf16x8*)(KsB + kOffB[f]);
      sA = __builtin_amdgcn_mfma_f32_32x32x16_bf16(a0, Qf[f], sA, 0, 0, 0);
      sB = __builtin_amdgcn_mfma_f32_32x32x16_bf16(a1, Qf[f], sB, 0, 0, 0);
    }
    __builtin_amdgcn_s_setprio(0);

    float mx[8];
#pragma unroll
    for (int r = 0; r < 8; ++r)
      mx[r] = fmaxf(fmaxf(sA[r], sA[r + 8]), fmaxf(sB[r], sB[r + 8]));
    mx[0] = fmaxf(mx[0], mx[4]); mx[1] = fmaxf(mx[1], mx[5]);
    mx[2] = fmaxf(mx[2], mx[6]); mx[3] = fmaxf(mx[3], mx[7]);
    mx[0] = fmaxf(fmaxf(mx[0], mx[1]), fmaxf(mx[2], mx[3]));
    const float mt = fmaxf(mx[0], __shfl_xor(mx[0], 32, 64));
    if (!__all(mt <= m + 10.0f)) {
      const float mn = fmaxf(m, mt);
      const float corr = ex2(m - mn);
      m = mn;
      lsum *= corr;
#pragma unroll
      for (int dt = 0; dt < 2; ++dt)
#pragma unroll
        for (int r = 0; r < 16; ++r) accO[dt][r] *= corr;
    }

    unsigned WA[8], WB[8];
    float s0 = 0.f, s1 = 0.f, s2 = 0.f, s3 = 0.f;
#pragma unroll
    for (int t = 0; t < 4; ++t) {
      float a0 = ex2(sA[4 * t + 0] - m), a1 = ex2(sA[4 * t + 1] - m);
      float a2 = ex2(sA[4 * t + 2] - m), a3 = ex2(sA[4 * t + 3] - m);
      WA[2 * t] = pk2(a0, a1); WA[2 * t + 1] = pk2(a2, a3);
      s0 += a0 + a1; s1 += a2 + a3;
      float b0 = ex2(sB[4 * t + 0] - m), b1 = ex2(sB[4 * t + 1] - m);
      float b2 = ex2(sB[4 * t + 2] - m), b3 = ex2(sB[4 * t + 3] - m);
      WB[2 * t] = pk2(b0, b1); WB[2 * t + 1] = pk2(b2, b3);
      s2 += b0 + b1; s3 += b2 + b3;
    }
    lsum += (s0 + s1) + (s2 + s3);

#pragma unroll
    for (int kc = 0; kc < 4; ++kc) {
      unsigned w0 = (kc < 2) ? WA[(kc & 1) * 4 + 0] : WB[(kc & 1) * 4 + 0];
      unsigned w1 = (kc < 2) ? WA[(kc & 1) * 4 + 1] : WB[(kc & 1) * 4 + 1];
      unsigned w2 = (kc < 2) ? WA[(kc & 1) * 4 + 2] : WB[(kc & 1) * 4 + 2];
      unsigned w3 = (kc < 2) ? WA[(kc & 1) * 4 + 3] : WB[(kc & 1) * 4 + 3];
      asm volatile("v_permlane32_swap_b32 %0, %1" : "+v"(w0), "+v"(w2));
      asm volatile("v_permlane32_swap_b32 %0, %1" : "+v"(w1), "+v"(w3));
      union { unsigned u[4]; bf16x8 v8; } pb;
      pb.u[0] = w0; pb.u[1] = w1; pb.u[2] = w2; pb.u[3] = w3;
      __builtin_amdgcn_s_setprio(1);
#pragma unroll
      for (int dt = 0; dt < 2; ++dt) {
        bf16x8 va = *(const bf16x8*)(VtB + vOff[kc][dt]);
        accO[dt] = __builtin_amdgcn_mfma_f32_32x32x16_bf16(va, pb.v8, accO[dt], 0, 0, 0);
      }
      __builtin_amdgcn_s_setprio(0);
    }

    asm volatile("s_waitcnt vmcnt(0)" ::: "memory");
    __builtin_amdgcn_s_barrier();
    __builtin_amdgcn_sched_barrier(0);
    cur ^= 1;
  }

  const float ltot = lsum + __shfl_xor(lsum, 32, 64);
  const float inv = 1.f / ltot;
  float* xrow = x + ((size_t)b * S_ + qb * 256 + w * 32 + ql) * D_ + h * 64;
#pragma unroll
  for (int dt = 0; dt < 2; ++dt)
#pragma unroll
    for (int g0 = 0; g0 < 4; ++g0) {
      float4 o;
      o.x = accO[dt][4 * g0 + 0] * inv;
      o.y = accO[dt][4 * g0 + 1] * inv;
      o.z = accO[dt][4 * g0 + 2] * inv;
      o.w = accO[dt][4 * g0 + 3] * inv;
      *(float4*)&xrow[dt * 32 + hi * 4 + g0 * 8] = o;
    }
}

// ---------------------------------------------------------------------------
extern "C" void kernel_launch(void* const* d_in, const int* in_sizes, int n_in,
                              void* d_out, int out_size, void* d_ws, size_t ws_size,
                              hipStream_t stream) {
  const float* query = (const float*)d_in[0];
  const float* key   = (const float*)d_in[1];
  const float* value = (const float*)d_in[2];
  const float* W_fk = (const float*)d_in[4];
  const float* b_fk = (const float*)d_in[5];
  const float* W0   = (const float*)d_in[6];
  const float* b0   = (const float*)d_in[7];
  const float* Wout = (const float*)d_in[8];
  const float* bout = (const float*)d_in[9];
  float* out = (float*)d_out;

  char* ws = (char*)d_ws;
  unsigned short* kfk_bf16 = (unsigned short*)ws;                // 8MB @ 0
  float* x_f32   = (float*)(ws + (16u << 20));                   // 16MB @ 16MB
  unsigned short* k_bf16  = (unsigned short*)(ws + (32u << 20)); // 8MB @ 32MB
  unsigned short* vT_bf16 = (unsigned short*)(ws + (40u << 20)); // 8MB @ 40MB, [b][d][s]
  unsigned short* q_bf16  = (unsigned short*)(ws + (48u << 20)); // 8MB @ 48MB

  // 1/sqrt(dk) * log2(e): softmax runs in exp2 domain
  const float qscale = 0.125f * 1.4426950408889634f;

  // A: kfk GEMM || v GEMM -> V^T || pool-q (independent, overlapped)
  phaseA_kernel<<<3072, 256, 0, stream>>>(key, W_fk, b_fk, kfk_bf16,
                                          value, W0, b0, vT_bf16,
                                          query, q_bf16, qscale);
  // B: k = pool(kfk_bf16)
  pool_k_kernel<<<2048, 256, 0, stream>>>(kfk_bf16, k_bf16);
  // C: attention -> f32 (8-wave shared-stream, 256-VGPR budget)
  attn8_kernel<<<dim3(B_ * H_ * (S_ / 256)), 512, 0, stream>>>(
      q_bf16, k_bf16, vT_bf16, x_f32);
  // D: out = x @ Wout + bout (plain bf16)
  gemm_out_kernel<<<512, 256, 0, stream>>>(x_f32, Wout, bout, out);
}